// Round 13
// baseline (64.239 us; speedup 1.0000x reference)
//
#include <hip/hip_runtime.h>

#define CAPS_EPS 1e-9f

typedef __fp16 half2_t __attribute__((ext_vector_type(2)));
typedef int int2v __attribute__((ext_vector_type(2)));

#if __has_builtin(__builtin_amdgcn_exp2f)
#define EXP2(x) __builtin_amdgcn_exp2f(x)
#else
#define EXP2(x) exp2f(x)
#endif
#define LOG2E 1.44269504f

__device__ __forceinline__ half2_t bc_h2(float f) {
    union { float f; half2_t h; } u; u.f = f; return u.h;
}
__device__ __forceinline__ float bc_f(half2_t h) {
    union { float f; half2_t h; } u; u.h = h; return u.f;
}

// DPP cross-lane (pure VALU): xor1=quad_perm(1,0,3,2)=0xB1, xor2=quad_perm(2,3,0,1)=0x4E,
// row_ror:4=0x124, row_ror:8=0x128. Sum-allreduce over 16 lanes: xor1,xor2 then
// ror4+ror8 (rotation direction irrelevant for a sum). Exact-partner xor4 that DPP
// can't express keeps ds_swizzle 0x101F.
template<int CTRL>
__device__ __forceinline__ float mov_dpp_f(float x) {
    return __builtin_bit_cast(float,
        __builtin_amdgcn_update_dpp(0, __builtin_bit_cast(int, x), CTRL, 0xF, 0xF, true));
}
template<int PAT>
__device__ __forceinline__ float mov_sw_f(float x) {
    return __builtin_bit_cast(float,
        __builtin_amdgcn_ds_swizzle(__builtin_bit_cast(int, x), PAT));
}
template<int CTRL>
__device__ __forceinline__ float xadd_dpp(float x) { return x + mov_dpp_f<CTRL>(x); }

// full 16-lane sum-allreduce, LDS-pipe-free
__device__ __forceinline__ float allred16(float x) {
    x = xadd_dpp<0xB1>(x);
    x = xadd_dpp<0x4E>(x);
    x = xadd_dpp<0x124>(x);
    x = xadd_dpp<0x128>(x);
    return x;
}

// lane[i] <-> lane[i^32]: VALU permlane32_swap on gfx950
__device__ __forceinline__ float xswap32(float x, int lane) {
#if __has_builtin(__builtin_amdgcn_permlane32_swap)
    const int xi = __builtin_bit_cast(int, x);
    int2v r = __builtin_amdgcn_permlane32_swap(xi, xi, false, false);
    return __builtin_bit_cast(float, (lane & 32) ? r[0] : r[1]);
#else
    return __shfl_xor(x, 32);
#endif
}

// lane[i] <-> lane[i^16]: VALU permlane16_swap on gfx950, else ds_swizzle xor16
__device__ __forceinline__ float xswap16(float x, int lane) {
#if __has_builtin(__builtin_amdgcn_permlane16_swap)
    const int xi = __builtin_bit_cast(int, x);
    int2v r = __builtin_amdgcn_permlane16_swap(xi, xi, false, false);
    return __builtin_bit_cast(float, (lane & 16) ? r[0] : r[1]);
#else
    return mov_sw_f<0x401F>(x);
#endif
}

// s += ck * f16(lo/hi of pk)  -- forced v_fma_mix_f32 (1 op, no separate cvt)
__device__ __forceinline__ void fmamix_lo(float& acc, float c, half2_t pk) {
    const int pi = __builtin_bit_cast(int, pk);
    asm("v_fma_mix_f32 %0, %1, %2, %0 op_sel_hi:[0,1,0]"
        : "+v"(acc) : "v"(c), "v"(pi));
}
__device__ __forceinline__ void fmamix_hi(float& acc, float c, half2_t pk) {
    const int pi = __builtin_bit_cast(int, pk);
    asm("v_fma_mix_f32 %0, %1, %2, %0 op_sel:[0,1,0] op_sel_hi:[0,1,0]"
        : "+v"(acc) : "v"(c), "v"(pi));
}

// tree sum-of-squares of 16 floats: depth ~6 instead of 16
__device__ __forceinline__ float sumsq16(const float* s) {
    float a0 = 0.0f, a1 = 0.0f, a2 = 0.0f, a3 = 0.0f;
    #pragma unroll
    for (int d = 0; d < 16; d += 4) {
        a0 = fmaf(s[d],     s[d],     a0);
        a1 = fmaf(s[d + 1], s[d + 1], a1);
        a2 = fmaf(s[d + 2], s[d + 2], a2);
        a3 = fmaf(s[d + 3], s[d + 3], a3);
    }
    return (a0 + a1) + (a2 + a3);
}

// ---------------------------------------------------------------------------
// Pre-pass: pack kernel weights f32 -> f16 q-pairs for v_dot2_f32_f16.
// wpk[((n*9+k)*16+c)*8 + r*2 + qh] = (W[n,k,c,2qh,r], W[n,k,c,2qh+1,r])
// ---------------------------------------------------------------------------
__global__ __launch_bounds__(256)
void pack_weights(const float* __restrict__ kern, half2_t* __restrict__ wpk) {
    const int t  = blockIdx.x * 256 + (int)threadIdx.x;   // 0..36863
    const int qh = t & 1;
    const int r  = (t >> 1) & 3;
    const int base = (t >> 3) * 16;                       // ((n*9+k)*16+c)*16
    const float f0 = kern[base + (2 * qh) * 4 + r];
    const float f1 = kern[base + (2 * qh + 1) * 4 + r];
    wpk[t] = __builtin_amdgcn_cvt_pkrtz(f0, f1);
}

// ---------------------------------------------------------------------------
// One workgroup (256 threads) per TWO output spatial positions (serial loop).
// Grid 1800 = 7.03 blocks/CU -> single scheduling round at 8-wave/SIMD
// residency (VGPR~60), no ragged second round / drain tail; position B's
// weight reads hit L1 (loaded by A). tid = n*16 + c.
// Votes f16-packed Vp[9][8] via v_dot2_f32_f16 (f32 accumulate); SV[16] f32
// k-sum makes iter-0's s-accum free. Weight loads software-pipelined one k
// ahead. s-accum uses forced v_fma_mix_f32. Softmax cross-lane on
// permlane16/32_swap (pure VALU). Barrier safety across the position loop:
// A's last poseH read precedes A's iter-1 barrier; B's staging writes come
// after A's iter-2 barrier.
// ---------------------------------------------------------------------------
__global__ __launch_bounds__(256, 2)
void caps_route(const float* __restrict__ poses,    // [4][32][32][16][4][4]
                const half2_t* __restrict__ wpk,    // packed weights (pre-pass)
                float* __restrict__ out)            // poses 921600 | acts 57600
{
    const int tid = (int)threadIdx.x;
    const int c   = tid & 15;              // input channel (lane-fast)
    const int n   = tid >> 4;              // output capsule
    const int lane = tid & 63;
    const int wv  = tid >> 6;              // wave id 0..3

    __shared__ float4 poseH[9 * 32];       // f16 q-pairs: [k][p-half][c]
    __shared__ float4 sbv[2][9 * 16];      // softmax partials [k][c] = {w0,w1,w2,w3}

    const float4* gf4 = reinterpret_cast<const float4*>(wpk + (size_t)n * 1152 + c * 8);

    for (int pp = 0; pp < 2; ++pp) {
        const int pos = blockIdx.x * 2 + pp;   // 0..3599
        const int b   = pos / 900;
        const int hw  = pos % 900;
        const int h   = hw / 30;
        const int w   = hw % 30;

        // prefetch k=0 weights (L1-hot for pp==1)
        float4 gA = gf4[0], gB = gf4[1];

        // ---------------- stage pose blocks, cvt to f16 (coalesced) ----------------
        for (int idx = tid; idx < 288; idx += 256) {
            const int k   = idx >> 5;          // 0..8
            const int rem = idx & 31;
            const int hh  = rem >> 4;          // p-half
            const int cc  = rem & 15;
            const int ki = k / 3, kj = k % 3;
            const float4* src = reinterpret_cast<const float4*>(
                poses + (size_t)(((b * 32 + h + ki) * 32) + (w + kj)) * 256);
            const float4 t0 = src[cc * 4 + hh * 2];
            const float4 t1 = src[cc * 4 + hh * 2 + 1];
            float4 o;
            o.x = bc_f(__builtin_amdgcn_cvt_pkrtz(t0.x, t0.y));
            o.y = bc_f(__builtin_amdgcn_cvt_pkrtz(t0.z, t0.w));
            o.z = bc_f(__builtin_amdgcn_cvt_pkrtz(t1.x, t1.y));
            o.w = bc_f(__builtin_amdgcn_cvt_pkrtz(t1.z, t1.w));
            poseH[k * 32 + hh * 16 + cc] = o;
        }
        __syncthreads();

        // ------- votes via dot2 (f16 in, f32 acc) + f32 k-sum SV (iter-0 fuse) -------
        half2_t Vp[9][8];
        float SV[16];
        #pragma unroll
        for (int d = 0; d < 16; ++d) SV[d] = 0.0f;
        #pragma unroll
        for (int k = 0; k < 9; ++k) {
            const float4 g0 = gA, g1 = gB;
            if (k < 8) { gA = gf4[(k + 1) * 32]; gB = gf4[(k + 1) * 32 + 1]; }
            const float4 t0 = poseH[k * 32 + c];
            const float4 t1 = poseH[k * 32 + 16 + c];
            half2_t ap[4][2] = {
                {bc_h2(t0.x), bc_h2(t0.y)}, {bc_h2(t0.z), bc_h2(t0.w)},
                {bc_h2(t1.x), bc_h2(t1.y)}, {bc_h2(t1.z), bc_h2(t1.w)} };
            half2_t ga[4][2] = {
                {bc_h2(g0.x), bc_h2(g0.y)}, {bc_h2(g0.z), bc_h2(g0.w)},
                {bc_h2(g1.x), bc_h2(g1.y)}, {bc_h2(g1.z), bc_h2(g1.w)} };
            #pragma unroll
            for (int p = 0; p < 4; ++p) {
                #pragma unroll
                for (int rh = 0; rh < 2; ++rh) {
                    float a0 = __builtin_amdgcn_fdot2(ap[p][0], ga[2 * rh][0], 0.0f, false);
                    a0 = __builtin_amdgcn_fdot2(ap[p][1], ga[2 * rh][1], a0, false);
                    float a1 = __builtin_amdgcn_fdot2(ap[p][0], ga[2 * rh + 1][0], 0.0f, false);
                    a1 = __builtin_amdgcn_fdot2(ap[p][1], ga[2 * rh + 1][1], a1, false);
                    const int d0 = p * 4 + 2 * rh;
                    SV[d0]     += a0;
                    SV[d0 + 1] += a1;
                    Vp[k][p * 2 + rh] = __builtin_amdgcn_cvt_pkrtz(a0, a1);
                }
            }
        }

        float b_log[9];                        // logits in log2 domain

        // -------- iter 0: ck == 1/16 -> allreduce directly on SV --------
        {
            float s[16];
            #pragma unroll
            for (int d = 0; d < 16; ++d) s[d] = allred16(SV[d]);

            const float n2 = sumsq16(s) * (1.0f / 256.0f);               // ||S/16||^2
            const float g = n2 * __builtin_amdgcn_rcpf(1.0f + n2)
                               * __builtin_amdgcn_rsqf(n2 + CAPS_EPS);
            const float gl2 = g * (0.0625f * LOG2E);                     // log2-domain

            half2_t spk[8];
            #pragma unroll
            for (int j = 0; j < 8; ++j)
                spk[j] = __builtin_amdgcn_cvt_pkrtz(s[2 * j], s[2 * j + 1]);
            #pragma unroll
            for (int k = 0; k < 9; ++k) {
                float dot = 0.0f;
                #pragma unroll
                for (int j = 0; j < 8; ++j)
                    dot = __builtin_amdgcn_fdot2(Vp[k][j], spk[j], dot, false);
                b_log[k] = gl2 * dot;
            }
        }

        // -------- iter 1: softmax + weighted accum + full allreduce --------
        {
            float eb[9], ebs[9];
            #pragma unroll
            for (int k = 0; k < 9; ++k) { eb[k] = EXP2(b_log[k]); ebs[k] = eb[k]; }
            #pragma unroll
            for (int k = 0; k < 9; ++k) {
                ebs[k] += xswap16(ebs[k], lane);           // xor16 (VALU permlane)
                ebs[k] += xswap32(ebs[k], lane);           // xor32 (VALU permlane)
            }
            if (lane < 16) {
                #pragma unroll
                for (int k = 0; k < 9; ++k)
                    reinterpret_cast<float*>(&sbv[0][k * 16 + c])[wv] = ebs[k];
            }
            __syncthreads();
            float ck[9];
            #pragma unroll
            for (int k = 0; k < 9; ++k) {
                const float4 t = sbv[0][k * 16 + c];
                const float tot = (t.x + t.y) + (t.z + t.w);
                ck[k] = eb[k] * __builtin_amdgcn_rcpf(tot);
            }

            float s[16];
            #pragma unroll
            for (int d = 0; d < 16; ++d) s[d] = 0.0f;
            #pragma unroll
            for (int k = 0; k < 9; ++k) {
                const float ckk = ck[k];
                #pragma unroll
                for (int j = 0; j < 8; ++j) {
                    fmamix_lo(s[2 * j],     ckk, Vp[k][j]);
                    fmamix_hi(s[2 * j + 1], ckk, Vp[k][j]);
                }
            }
            #pragma unroll
            for (int d = 0; d < 16; ++d) s[d] = allred16(s[d]);

            const float n2S = sumsq16(s);
            const float g = n2S * __builtin_amdgcn_rcpf(1.0f + n2S)
                                * __builtin_amdgcn_rsqf(n2S + CAPS_EPS);
            const float gl2 = g * LOG2E;

            half2_t spk[8];
            #pragma unroll
            for (int j = 0; j < 8; ++j)
                spk[j] = __builtin_amdgcn_cvt_pkrtz(s[2 * j], s[2 * j + 1]);
            #pragma unroll
            for (int k = 0; k < 9; ++k) {
                float dot = 0.0f;
                #pragma unroll
                for (int j = 0; j < 8; ++j)
                    dot = __builtin_amdgcn_fdot2(Vp[k][j], spk[j], dot, false);
                b_log[k] = fmaf(gl2, dot, b_log[k]);
            }
        }

        // -------- iter 2: reduce-scatter (lane c keeps s[c]), no allgather --------
        {
            float eb[9], ebs[9];
            #pragma unroll
            for (int k = 0; k < 9; ++k) { eb[k] = EXP2(b_log[k]); ebs[k] = eb[k]; }
            #pragma unroll
            for (int k = 0; k < 9; ++k) {
                ebs[k] += xswap16(ebs[k], lane);
                ebs[k] += xswap32(ebs[k], lane);
            }
            if (lane < 16) {
                #pragma unroll
                for (int k = 0; k < 9; ++k)
                    reinterpret_cast<float*>(&sbv[1][k * 16 + c])[wv] = ebs[k];
            }
            __syncthreads();
            float ck[9];
            #pragma unroll
            for (int k = 0; k < 9; ++k) {
                const float4 t = sbv[1][k * 16 + c];
                const float tot = (t.x + t.y) + (t.z + t.w);
                ck[k] = eb[k] * __builtin_amdgcn_rcpf(tot);
            }

            float s[16];
            #pragma unroll
            for (int d = 0; d < 16; ++d) s[d] = 0.0f;
            #pragma unroll
            for (int k = 0; k < 9; ++k) {
                const float ckk = ck[k];
                #pragma unroll
                for (int j = 0; j < 8; ++j) {
                    fmamix_lo(s[2 * j],     ckk, Vp[k][j]);
                    fmamix_hi(s[2 * j + 1], ckk, Vp[k][j]);
                }
            }
            // recursive-halving reduce-scatter: send the half the PARTNER keeps
            const bool k8 = (c & 8) != 0;
            float t8[8];
            #pragma unroll
            for (int j = 0; j < 8; ++j) {
                const float keep = k8 ? s[j + 8] : s[j];
                const float send = k8 ? s[j] : s[j + 8];
                t8[j] = keep + mov_dpp_f<0x128>(send);     // ror8 == xor8 within 16
            }
            const bool k4 = (c & 4) != 0;
            float t4[4];
            #pragma unroll
            for (int j = 0; j < 4; ++j) {
                const float keep = k4 ? t8[j + 4] : t8[j];
                const float send = k4 ? t8[j] : t8[j + 4];
                t4[j] = keep + mov_sw_f<0x101F>(send);     // exact xor4 (swizzle)
            }
            const bool k2 = (c & 2) != 0;
            float t2[2];
            #pragma unroll
            for (int j = 0; j < 2; ++j) {
                const float keep = k2 ? t4[j + 2] : t4[j];
                const float send = k2 ? t4[j] : t4[j + 2];
                t2[j] = keep + mov_dpp_f<0x4E>(send);
            }
            const bool k1 = (c & 1) != 0;
            const float z = (k1 ? t2[1] : t2[0]) + mov_dpp_f<0xB1>(k1 ? t2[0] : t2[1]);
            // z == fully-reduced s[c] on lane c

            const float n2 = allred16(z * z);              // ||s||^2 over the 16-group

            const float scale = n2 * __builtin_amdgcn_rcpf(1.0f + n2)
                                   * __builtin_amdgcn_rsqf(n2 + CAPS_EPS);
            out[(size_t)pos * 256 + n * 16 + c] = z * scale;   // fully coalesced

            if (c == 0) {
                const float m2 = n2 * scale * scale;           // ||v||^2
                const float sc2 = m2 * __builtin_amdgcn_rcpf(1.0f + m2)
                                     * __builtin_amdgcn_rsqf(m2 + CAPS_EPS);
                out[921600 + (size_t)pos * 16 + n] = sqrtf(m2 * sc2 * sc2 + CAPS_EPS);
            }
        }
    }
}

extern "C" void kernel_launch(void* const* d_in, const int* in_sizes, int n_in,
                              void* d_out, int out_size, void* d_ws, size_t ws_size,
                              hipStream_t stream) {
    const float* poses = (const float*)d_in[0];
    // d_in[1] = input_activations: unused by the reference computation
    const float* kern  = (const float*)d_in[2];
    float* out = (float*)d_out;
    half2_t* wpk = (half2_t*)d_ws;         // 73728 B of scratch

    pack_weights<<<dim3(144), dim3(256), 0, stream>>>(kern, wpk);
    caps_route<<<dim3(1800), dim3(256), 0, stream>>>(poses, wpk, out);
}

// Round 14
// 56.232 us; speedup vs baseline: 1.1424x; 1.1424x over previous
//
#include <hip/hip_runtime.h>

#define CAPS_EPS 1e-9f

typedef __fp16 half2_t __attribute__((ext_vector_type(2)));
typedef int int2v __attribute__((ext_vector_type(2)));

#if __has_builtin(__builtin_amdgcn_exp2f)
#define EXP2(x) __builtin_amdgcn_exp2f(x)
#else
#define EXP2(x) exp2f(x)
#endif
#define LOG2E 1.44269504f

__device__ __forceinline__ half2_t bc_h2(float f) {
    union { float f; half2_t h; } u; u.f = f; return u.h;
}
__device__ __forceinline__ float bc_f(half2_t h) {
    union { float f; half2_t h; } u; u.h = h; return u.f;
}

// DPP cross-lane (pure VALU): xor1=quad_perm(1,0,3,2)=0xB1, xor2=quad_perm(2,3,0,1)=0x4E,
// row_ror:4=0x124, row_ror:8=0x128. Sum-allreduce over 16 lanes: xor1,xor2 then
// ror4+ror8 (rotation direction irrelevant for a sum). Exact-partner xor4 that DPP
// can't express keeps ds_swizzle 0x101F.
template<int CTRL>
__device__ __forceinline__ float mov_dpp_f(float x) {
    return __builtin_bit_cast(float,
        __builtin_amdgcn_update_dpp(0, __builtin_bit_cast(int, x), CTRL, 0xF, 0xF, true));
}
template<int PAT>
__device__ __forceinline__ float mov_sw_f(float x) {
    return __builtin_bit_cast(float,
        __builtin_amdgcn_ds_swizzle(__builtin_bit_cast(int, x), PAT));
}
template<int CTRL>
__device__ __forceinline__ float xadd_dpp(float x) { return x + mov_dpp_f<CTRL>(x); }

// full 16-lane sum-allreduce, LDS-pipe-free
__device__ __forceinline__ float allred16(float x) {
    x = xadd_dpp<0xB1>(x);
    x = xadd_dpp<0x4E>(x);
    x = xadd_dpp<0x124>(x);
    x = xadd_dpp<0x128>(x);
    return x;
}

// lane[i] <-> lane[i^32]: VALU permlane32_swap on gfx950
__device__ __forceinline__ float xswap32(float x, int lane) {
#if __has_builtin(__builtin_amdgcn_permlane32_swap)
    const int xi = __builtin_bit_cast(int, x);
    int2v r = __builtin_amdgcn_permlane32_swap(xi, xi, false, false);
    return __builtin_bit_cast(float, (lane & 32) ? r[0] : r[1]);
#else
    return __shfl_xor(x, 32);
#endif
}

// lane[i] <-> lane[i^16]: VALU permlane16_swap on gfx950, else ds_swizzle xor16
__device__ __forceinline__ float xswap16(float x, int lane) {
#if __has_builtin(__builtin_amdgcn_permlane16_swap)
    const int xi = __builtin_bit_cast(int, x);
    int2v r = __builtin_amdgcn_permlane16_swap(xi, xi, false, false);
    return __builtin_bit_cast(float, (lane & 16) ? r[0] : r[1]);
#else
    return mov_sw_f<0x401F>(x);
#endif
}

// s += ck * f16(lo/hi of pk)  -- forced v_fma_mix_f32 (1 op, no separate cvt)
__device__ __forceinline__ void fmamix_lo(float& acc, float c, half2_t pk) {
    const int pi = __builtin_bit_cast(int, pk);
    asm("v_fma_mix_f32 %0, %1, %2, %0 op_sel_hi:[0,1,0]"
        : "+v"(acc) : "v"(c), "v"(pi));
}
__device__ __forceinline__ void fmamix_hi(float& acc, float c, half2_t pk) {
    const int pi = __builtin_bit_cast(int, pk);
    asm("v_fma_mix_f32 %0, %1, %2, %0 op_sel:[0,1,0] op_sel_hi:[0,1,0]"
        : "+v"(acc) : "v"(c), "v"(pi));
}

// tree sum-of-squares of 16 floats: depth ~6 instead of 16
__device__ __forceinline__ float sumsq16(const float* s) {
    float a0 = 0.0f, a1 = 0.0f, a2 = 0.0f, a3 = 0.0f;
    #pragma unroll
    for (int d = 0; d < 16; d += 4) {
        a0 = fmaf(s[d],     s[d],     a0);
        a1 = fmaf(s[d + 1], s[d + 1], a1);
        a2 = fmaf(s[d + 2], s[d + 2], a2);
        a3 = fmaf(s[d + 3], s[d + 3], a3);
    }
    return (a0 + a1) + (a2 + a3);
}

// ---------------------------------------------------------------------------
// Pre-pass: pack kernel weights f32 -> f16 q-pairs for v_dot2_f32_f16.
// wpk[((n*9+k)*16+c)*8 + r*2 + qh] = (W[n,k,c,2qh,r], W[n,k,c,2qh+1,r])
// ---------------------------------------------------------------------------
__global__ __launch_bounds__(256)
void pack_weights(const float* __restrict__ kern, half2_t* __restrict__ wpk) {
    const int t  = blockIdx.x * 256 + (int)threadIdx.x;   // 0..36863
    const int qh = t & 1;
    const int r  = (t >> 1) & 3;
    const int base = (t >> 3) * 16;                       // ((n*9+k)*16+c)*16
    const float f0 = kern[base + (2 * qh) * 4 + r];
    const float f1 = kern[base + (2 * qh + 1) * 4 + r];
    wpk[t] = __builtin_amdgcn_cvt_pkrtz(f0, f1);
}

// ---------------------------------------------------------------------------
// One workgroup (256 threads) per output spatial position. tid = n*16 + c.
// Votes f16-packed Vp[9][8] via v_dot2_f32_f16 (f32 accumulate); SV[16] f32
// k-sum makes iter-0's s-accum free. Weight loads software-pipelined one k
// ahead. s-accum phases use forced v_fma_mix_f32 (f16 operand, f32 accum,
// 1 op/element). Softmax cross-lane on permlane16/32_swap (pure VALU).
// NOTE (r13 lesson): do NOT wrap the body in a position loop — it inflates
// live ranges, VGPR 60 -> 128, occupancy halves, 14% slower. This exact
// structure gets VGPR=60 / occ 34% / 56.3 us.
// ---------------------------------------------------------------------------
__global__ __launch_bounds__(256, 2)
void caps_route(const float* __restrict__ poses,    // [4][32][32][16][4][4]
                const half2_t* __restrict__ wpk,    // packed weights (pre-pass)
                float* __restrict__ out)            // poses 921600 | acts 57600
{
    const int pos = blockIdx.x;            // 0..3599
    const int b   = pos / 900;
    const int hw  = pos % 900;
    const int h   = hw / 30;
    const int w   = hw % 30;

    const int tid = (int)threadIdx.x;
    const int c   = tid & 15;              // input channel (lane-fast)
    const int n   = tid >> 4;              // output capsule
    const int lane = tid & 63;

    __shared__ float4 poseH[9 * 32];       // f16 q-pairs: [k][p-half][c]
    __shared__ float4 sbv[2][9 * 16];      // softmax partials [k][c] = {w0,w1,w2,w3}

    // weight pointer + prefetch k=0 BEFORE staging (hides under pose loads)
    const float4* gf4 = reinterpret_cast<const float4*>(wpk + (size_t)n * 1152 + c * 8);
    float4 gA = gf4[0], gB = gf4[1];

    // ---------------- stage pose blocks, cvt to f16 (coalesced) ----------------
    for (int idx = tid; idx < 288; idx += 256) {
        const int k   = idx >> 5;          // 0..8
        const int rem = idx & 31;
        const int hh  = rem >> 4;          // p-half
        const int cc  = rem & 15;
        const int ki = k / 3, kj = k % 3;
        const float4* src = reinterpret_cast<const float4*>(
            poses + (size_t)(((b * 32 + h + ki) * 32) + (w + kj)) * 256);
        const float4 t0 = src[cc * 4 + hh * 2];
        const float4 t1 = src[cc * 4 + hh * 2 + 1];
        float4 o;
        o.x = bc_f(__builtin_amdgcn_cvt_pkrtz(t0.x, t0.y));
        o.y = bc_f(__builtin_amdgcn_cvt_pkrtz(t0.z, t0.w));
        o.z = bc_f(__builtin_amdgcn_cvt_pkrtz(t1.x, t1.y));
        o.w = bc_f(__builtin_amdgcn_cvt_pkrtz(t1.z, t1.w));
        poseH[k * 32 + hh * 16 + cc] = o;
    }
    __syncthreads();

    // ------- votes via dot2 (f16 in, f32 acc) + f32 k-sum SV (iter-0 fuse) -------
    half2_t Vp[9][8];
    float SV[16];
    #pragma unroll
    for (int d = 0; d < 16; ++d) SV[d] = 0.0f;
    #pragma unroll
    for (int k = 0; k < 9; ++k) {
        const float4 g0 = gA, g1 = gB;
        if (k < 8) { gA = gf4[(k + 1) * 32]; gB = gf4[(k + 1) * 32 + 1]; }  // prefetch k+1
        const float4 t0 = poseH[k * 32 + c];
        const float4 t1 = poseH[k * 32 + 16 + c];
        half2_t ap[4][2] = {
            {bc_h2(t0.x), bc_h2(t0.y)}, {bc_h2(t0.z), bc_h2(t0.w)},
            {bc_h2(t1.x), bc_h2(t1.y)}, {bc_h2(t1.z), bc_h2(t1.w)} };
        half2_t ga[4][2] = {
            {bc_h2(g0.x), bc_h2(g0.y)}, {bc_h2(g0.z), bc_h2(g0.w)},
            {bc_h2(g1.x), bc_h2(g1.y)}, {bc_h2(g1.z), bc_h2(g1.w)} };
        #pragma unroll
        for (int p = 0; p < 4; ++p) {
            #pragma unroll
            for (int rh = 0; rh < 2; ++rh) {
                float a0 = __builtin_amdgcn_fdot2(ap[p][0], ga[2 * rh][0], 0.0f, false);
                a0 = __builtin_amdgcn_fdot2(ap[p][1], ga[2 * rh][1], a0, false);
                float a1 = __builtin_amdgcn_fdot2(ap[p][0], ga[2 * rh + 1][0], 0.0f, false);
                a1 = __builtin_amdgcn_fdot2(ap[p][1], ga[2 * rh + 1][1], a1, false);
                const int d0 = p * 4 + 2 * rh;
                SV[d0]     += a0;
                SV[d0 + 1] += a1;
                Vp[k][p * 2 + rh] = __builtin_amdgcn_cvt_pkrtz(a0, a1);
            }
        }
    }

    float b_log[9];                        // logits in log2 domain
    const int wv = tid >> 6;               // wave id 0..3

    // -------- iter 0: ck == 1/16 -> allreduce directly on SV --------
    {
        float s[16];
        #pragma unroll
        for (int d = 0; d < 16; ++d) s[d] = allred16(SV[d]);

        const float n2 = sumsq16(s) * (1.0f / 256.0f);               // ||S/16||^2
        const float g = n2 * __builtin_amdgcn_rcpf(1.0f + n2)
                           * __builtin_amdgcn_rsqf(n2 + CAPS_EPS);
        const float gl2 = g * (0.0625f * LOG2E);                     // log2-domain

        half2_t spk[8];
        #pragma unroll
        for (int j = 0; j < 8; ++j)
            spk[j] = __builtin_amdgcn_cvt_pkrtz(s[2 * j], s[2 * j + 1]);
        #pragma unroll
        for (int k = 0; k < 9; ++k) {
            float dot = 0.0f;
            #pragma unroll
            for (int j = 0; j < 8; ++j)
                dot = __builtin_amdgcn_fdot2(Vp[k][j], spk[j], dot, false);
            b_log[k] = gl2 * dot;
        }
    }

    // -------- iter 1: softmax + weighted accum + full allreduce --------
    {
        float eb[9], ebs[9];
        #pragma unroll
        for (int k = 0; k < 9; ++k) { eb[k] = EXP2(b_log[k]); ebs[k] = eb[k]; }
        #pragma unroll
        for (int k = 0; k < 9; ++k) {
            ebs[k] += xswap16(ebs[k], lane);           // xor16 (VALU permlane)
            ebs[k] += xswap32(ebs[k], lane);           // xor32 (VALU permlane)
        }
        if (lane < 16) {
            #pragma unroll
            for (int k = 0; k < 9; ++k)
                reinterpret_cast<float*>(&sbv[0][k * 16 + c])[wv] = ebs[k];
        }
        __syncthreads();
        float ck[9];
        #pragma unroll
        for (int k = 0; k < 9; ++k) {
            const float4 t = sbv[0][k * 16 + c];
            const float tot = (t.x + t.y) + (t.z + t.w);
            ck[k] = eb[k] * __builtin_amdgcn_rcpf(tot);
        }

        float s[16];
        #pragma unroll
        for (int d = 0; d < 16; ++d) s[d] = 0.0f;
        #pragma unroll
        for (int k = 0; k < 9; ++k) {
            const float ckk = ck[k];
            #pragma unroll
            for (int j = 0; j < 8; ++j) {
                fmamix_lo(s[2 * j],     ckk, Vp[k][j]);
                fmamix_hi(s[2 * j + 1], ckk, Vp[k][j]);
            }
        }
        #pragma unroll
        for (int d = 0; d < 16; ++d) s[d] = allred16(s[d]);

        const float n2S = sumsq16(s);
        const float g = n2S * __builtin_amdgcn_rcpf(1.0f + n2S)
                            * __builtin_amdgcn_rsqf(n2S + CAPS_EPS);
        const float gl2 = g * LOG2E;

        half2_t spk[8];
        #pragma unroll
        for (int j = 0; j < 8; ++j)
            spk[j] = __builtin_amdgcn_cvt_pkrtz(s[2 * j], s[2 * j + 1]);
        #pragma unroll
        for (int k = 0; k < 9; ++k) {
            float dot = 0.0f;
            #pragma unroll
            for (int j = 0; j < 8; ++j)
                dot = __builtin_amdgcn_fdot2(Vp[k][j], spk[j], dot, false);
            b_log[k] = fmaf(gl2, dot, b_log[k]);
        }
    }

    // -------- iter 2: reduce-scatter (lane c keeps s[c]), no allgather --------
    {
        float eb[9], ebs[9];
        #pragma unroll
        for (int k = 0; k < 9; ++k) { eb[k] = EXP2(b_log[k]); ebs[k] = eb[k]; }
        #pragma unroll
        for (int k = 0; k < 9; ++k) {
            ebs[k] += xswap16(ebs[k], lane);
            ebs[k] += xswap32(ebs[k], lane);
        }
        if (lane < 16) {
            #pragma unroll
            for (int k = 0; k < 9; ++k)
                reinterpret_cast<float*>(&sbv[1][k * 16 + c])[wv] = ebs[k];
        }
        __syncthreads();
        float ck[9];
        #pragma unroll
        for (int k = 0; k < 9; ++k) {
            const float4 t = sbv[1][k * 16 + c];
            const float tot = (t.x + t.y) + (t.z + t.w);
            ck[k] = eb[k] * __builtin_amdgcn_rcpf(tot);
        }

        float s[16];
        #pragma unroll
        for (int d = 0; d < 16; ++d) s[d] = 0.0f;
        #pragma unroll
        for (int k = 0; k < 9; ++k) {
            const float ckk = ck[k];
            #pragma unroll
            for (int j = 0; j < 8; ++j) {
                fmamix_lo(s[2 * j],     ckk, Vp[k][j]);
                fmamix_hi(s[2 * j + 1], ckk, Vp[k][j]);
            }
        }
        // recursive-halving reduce-scatter: send the half the PARTNER keeps
        const bool k8 = (c & 8) != 0;
        float t8[8];
        #pragma unroll
        for (int j = 0; j < 8; ++j) {
            const float keep = k8 ? s[j + 8] : s[j];
            const float send = k8 ? s[j] : s[j + 8];
            t8[j] = keep + mov_dpp_f<0x128>(send);     // ror8 == xor8 within 16
        }
        const bool k4 = (c & 4) != 0;
        float t4[4];
        #pragma unroll
        for (int j = 0; j < 4; ++j) {
            const float keep = k4 ? t8[j + 4] : t8[j];
            const float send = k4 ? t8[j] : t8[j + 4];
            t4[j] = keep + mov_sw_f<0x101F>(send);     // exact xor4 (swizzle)
        }
        const bool k2 = (c & 2) != 0;
        float t2[2];
        #pragma unroll
        for (int j = 0; j < 2; ++j) {
            const float keep = k2 ? t4[j + 2] : t4[j];
            const float send = k2 ? t4[j] : t4[j + 2];
            t2[j] = keep + mov_dpp_f<0x4E>(send);
        }
        const bool k1 = (c & 1) != 0;
        const float z = (k1 ? t2[1] : t2[0]) + mov_dpp_f<0xB1>(k1 ? t2[0] : t2[1]);
        // z == fully-reduced s[c] on lane c

        const float n2 = allred16(z * z);              // ||s||^2 over the 16-group

        const float scale = n2 * __builtin_amdgcn_rcpf(1.0f + n2)
                               * __builtin_amdgcn_rsqf(n2 + CAPS_EPS);
        out[(size_t)pos * 256 + n * 16 + c] = z * scale;   // fully coalesced

        if (c == 0) {
            const float m2 = n2 * scale * scale;           // ||v||^2
            const float sc2 = m2 * __builtin_amdgcn_rcpf(1.0f + m2)
                                 * __builtin_amdgcn_rsqf(m2 + CAPS_EPS);
            out[921600 + (size_t)pos * 16 + n] = sqrtf(m2 * sc2 * sc2 + CAPS_EPS);
        }
    }
}

extern "C" void kernel_launch(void* const* d_in, const int* in_sizes, int n_in,
                              void* d_out, int out_size, void* d_ws, size_t ws_size,
                              hipStream_t stream) {
    const float* poses = (const float*)d_in[0];
    // d_in[1] = input_activations: unused by the reference computation
    const float* kern  = (const float*)d_in[2];
    float* out = (float*)d_out;
    half2_t* wpk = (half2_t*)d_ws;         // 73728 B of scratch

    pack_weights<<<dim3(144), dim3(256), 0, stream>>>(kern, wpk);
    caps_route<<<dim3(3600), dim3(256), 0, stream>>>(poses, wpk, out);
}

// Round 15
// 53.191 us; speedup vs baseline: 1.2077x; 1.0572x over previous
//
#include <hip/hip_runtime.h>

#define CAPS_EPS 1e-9f

typedef __fp16 half2_t __attribute__((ext_vector_type(2)));
typedef int int2v __attribute__((ext_vector_type(2)));

#if __has_builtin(__builtin_amdgcn_exp2f)
#define EXP2(x) __builtin_amdgcn_exp2f(x)
#else
#define EXP2(x) exp2f(x)
#endif
#define LOG2E 1.44269504f

__device__ __forceinline__ half2_t bc_h2(float f) {
    union { float f; half2_t h; } u; u.f = f; return u.h;
}
__device__ __forceinline__ float bc_f(half2_t h) {
    union { float f; half2_t h; } u; u.h = h; return u.f;
}

// DPP cross-lane (pure VALU): xor1=quad_perm(1,0,3,2)=0xB1, xor2=quad_perm(2,3,0,1)=0x4E,
// row_ror:4=0x124, row_ror:8=0x128. Sum-allreduce over 16 lanes: xor1,xor2 then
// ror4+ror8 (rotation direction irrelevant for a sum). Exact-partner xor4 that DPP
// can't express keeps ds_swizzle 0x101F.
template<int CTRL>
__device__ __forceinline__ float mov_dpp_f(float x) {
    return __builtin_bit_cast(float,
        __builtin_amdgcn_update_dpp(0, __builtin_bit_cast(int, x), CTRL, 0xF, 0xF, true));
}
template<int CTRL>
__device__ __forceinline__ half2_t mov_dpp_h2(half2_t x) {
    return __builtin_bit_cast(half2_t,
        __builtin_amdgcn_update_dpp(0, __builtin_bit_cast(int, x), CTRL, 0xF, 0xF, true));
}
template<int PAT>
__device__ __forceinline__ float mov_sw_f(float x) {
    return __builtin_bit_cast(float,
        __builtin_amdgcn_ds_swizzle(__builtin_bit_cast(int, x), PAT));
}
template<int CTRL>
__device__ __forceinline__ float xadd_dpp(float x) { return x + mov_dpp_f<CTRL>(x); }

// full 16-lane f32 sum-allreduce, LDS-pipe-free
__device__ __forceinline__ float allred16(float x) {
    x = xadd_dpp<0xB1>(x);
    x = xadd_dpp<0x4E>(x);
    x = xadd_dpp<0x124>(x);
    x = xadd_dpp<0x128>(x);
    return x;
}
// packed-f16 16-lane sum-allreduce (dpp mov + v_pk_add_f16 per round)
__device__ __forceinline__ half2_t allred16_pk(half2_t x) {
    x = x + mov_dpp_h2<0xB1>(x);
    x = x + mov_dpp_h2<0x4E>(x);
    x = x + mov_dpp_h2<0x124>(x);
    x = x + mov_dpp_h2<0x128>(x);
    return x;
}

// lane[i] <-> lane[i^32]: VALU permlane32_swap on gfx950
__device__ __forceinline__ float xswap32(float x, int lane) {
#if __has_builtin(__builtin_amdgcn_permlane32_swap)
    const int xi = __builtin_bit_cast(int, x);
    int2v r = __builtin_amdgcn_permlane32_swap(xi, xi, false, false);
    return __builtin_bit_cast(float, (lane & 32) ? r[0] : r[1]);
#else
    return __shfl_xor(x, 32);
#endif
}
// lane[i] <-> lane[i^16]: VALU permlane16_swap on gfx950
__device__ __forceinline__ float xswap16(float x, int lane) {
#if __has_builtin(__builtin_amdgcn_permlane16_swap)
    const int xi = __builtin_bit_cast(int, x);
    int2v r = __builtin_amdgcn_permlane16_swap(xi, xi, false, false);
    return __builtin_bit_cast(float, (lane & 16) ? r[0] : r[1]);
#else
    return mov_sw_f<0x401F>(x);
#endif
}

// s += ck * f16(lo/hi of pk)  -- forced v_fma_mix_f32 (1 op, no separate cvt)
__device__ __forceinline__ void fmamix_lo(float& acc, float c, half2_t pk) {
    const int pi = __builtin_bit_cast(int, pk);
    asm("v_fma_mix_f32 %0, %1, %2, %0 op_sel_hi:[0,1,0]"
        : "+v"(acc) : "v"(c), "v"(pi));
}
__device__ __forceinline__ void fmamix_hi(float& acc, float c, half2_t pk) {
    const int pi = __builtin_bit_cast(int, pk);
    asm("v_fma_mix_f32 %0, %1, %2, %0 op_sel:[0,1,0] op_sel_hi:[0,1,0]"
        : "+v"(acc) : "v"(c), "v"(pi));
}
// acc = a*b + acc, packed f16 -- forced v_pk_fma_f16
__device__ __forceinline__ void pkfma(half2_t& acc, half2_t a, half2_t b) {
    int ai = __builtin_bit_cast(int, a);
    int bi = __builtin_bit_cast(int, b);
    int ci = __builtin_bit_cast(int, acc);
    asm("v_pk_fma_f16 %0, %1, %2, %0" : "+v"(ci) : "v"(ai), "v"(bi));
    acc = __builtin_bit_cast(half2_t, ci);
}

// ---------------------------------------------------------------------------
// Pre-pass: pack kernel weights f32 -> f16 q-pairs for v_dot2_f32_f16.
// wpk[((n*9+k)*16+c)*8 + r*2 + qh] = (W[n,k,c,2qh,r], W[n,k,c,2qh+1,r])
// ---------------------------------------------------------------------------
__global__ __launch_bounds__(256)
void pack_weights(const float* __restrict__ kern, half2_t* __restrict__ wpk) {
    const int t  = blockIdx.x * 256 + (int)threadIdx.x;   // 0..36863
    const int qh = t & 1;
    const int r  = (t >> 1) & 3;
    const int base = (t >> 3) * 16;                       // ((n*9+k)*16+c)*16
    const float f0 = kern[base + (2 * qh) * 4 + r];
    const float f1 = kern[base + (2 * qh + 1) * 4 + r];
    wpk[t] = __builtin_amdgcn_cvt_pkrtz(f0, f1);
}

// ---------------------------------------------------------------------------
// One workgroup (256 threads) per output spatial position. tid = n*16 + c.
// Votes f16-packed Vp[9][8] via v_dot2_f32_f16 (f32 accumulate). SVp = packed
// f16 k-sum (v_pk_add_f16); iter-0 allreduces it PACKED and uses dot2-sumsq --
// zero cvt. iter-1 s-accum via v_pk_fma_f16 + packed allreduce (logit path
// only; f16 accumulation error ~1e-3 on logits is benign). iter-2 (output
// path) stays f32 fma_mix + f32 reduce-scatter.
// NOTE (r13 lesson): no position loop -- inflates live ranges, VGPR 60->128.
// ---------------------------------------------------------------------------
__global__ __launch_bounds__(256, 2)
void caps_route(const float* __restrict__ poses,    // [4][32][32][16][4][4]
                const half2_t* __restrict__ wpk,    // packed weights (pre-pass)
                float* __restrict__ out)            // poses 921600 | acts 57600
{
    const int pos = blockIdx.x;            // 0..3599
    const int b   = pos / 900;
    const int hw  = pos % 900;
    const int h   = hw / 30;
    const int w   = hw % 30;

    const int tid = (int)threadIdx.x;
    const int c   = tid & 15;              // input channel (lane-fast)
    const int n   = tid >> 4;              // output capsule
    const int lane = tid & 63;

    __shared__ float4 poseH[9 * 32];       // f16 q-pairs: [k][p-half][c]
    __shared__ float4 sbv[2][9 * 16];      // softmax partials [k][c] = {w0,w1,w2,w3}

    // weight pointer + prefetch k=0 BEFORE staging (hides under pose loads)
    const float4* gf4 = reinterpret_cast<const float4*>(wpk + (size_t)n * 1152 + c * 8);
    float4 gA = gf4[0], gB = gf4[1];

    // ---------------- stage pose blocks, cvt to f16 (coalesced) ----------------
    for (int idx = tid; idx < 288; idx += 256) {
        const int k   = idx >> 5;          // 0..8
        const int rem = idx & 31;
        const int hh  = rem >> 4;          // p-half
        const int cc  = rem & 15;
        const int ki = k / 3, kj = k % 3;
        const float4* src = reinterpret_cast<const float4*>(
            poses + (size_t)(((b * 32 + h + ki) * 32) + (w + kj)) * 256);
        const float4 t0 = src[cc * 4 + hh * 2];
        const float4 t1 = src[cc * 4 + hh * 2 + 1];
        float4 o;
        o.x = bc_f(__builtin_amdgcn_cvt_pkrtz(t0.x, t0.y));
        o.y = bc_f(__builtin_amdgcn_cvt_pkrtz(t0.z, t0.w));
        o.z = bc_f(__builtin_amdgcn_cvt_pkrtz(t1.x, t1.y));
        o.w = bc_f(__builtin_amdgcn_cvt_pkrtz(t1.z, t1.w));
        poseH[k * 32 + hh * 16 + cc] = o;
    }
    __syncthreads();

    // ------- votes via dot2 (f16 in, f32 acc) + PACKED f16 k-sum SVp -------
    half2_t Vp[9][8];
    half2_t SVp[8];
    #pragma unroll
    for (int j = 0; j < 8; ++j) SVp[j] = bc_h2(0.0f);
    #pragma unroll
    for (int k = 0; k < 9; ++k) {
        const float4 g0 = gA, g1 = gB;
        if (k < 8) { gA = gf4[(k + 1) * 32]; gB = gf4[(k + 1) * 32 + 1]; }  // prefetch k+1
        const float4 t0 = poseH[k * 32 + c];
        const float4 t1 = poseH[k * 32 + 16 + c];
        half2_t ap[4][2] = {
            {bc_h2(t0.x), bc_h2(t0.y)}, {bc_h2(t0.z), bc_h2(t0.w)},
            {bc_h2(t1.x), bc_h2(t1.y)}, {bc_h2(t1.z), bc_h2(t1.w)} };
        half2_t ga[4][2] = {
            {bc_h2(g0.x), bc_h2(g0.y)}, {bc_h2(g0.z), bc_h2(g0.w)},
            {bc_h2(g1.x), bc_h2(g1.y)}, {bc_h2(g1.z), bc_h2(g1.w)} };
        #pragma unroll
        for (int p = 0; p < 4; ++p) {
            #pragma unroll
            for (int rh = 0; rh < 2; ++rh) {
                float a0 = __builtin_amdgcn_fdot2(ap[p][0], ga[2 * rh][0], 0.0f, false);
                a0 = __builtin_amdgcn_fdot2(ap[p][1], ga[2 * rh][1], a0, false);
                float a1 = __builtin_amdgcn_fdot2(ap[p][0], ga[2 * rh + 1][0], 0.0f, false);
                a1 = __builtin_amdgcn_fdot2(ap[p][1], ga[2 * rh + 1][1], a1, false);
                const half2_t v2 = __builtin_amdgcn_cvt_pkrtz(a0, a1);
                Vp[k][p * 2 + rh] = v2;
                SVp[p * 2 + rh] = SVp[p * 2 + rh] + v2;    // v_pk_add_f16
            }
        }
    }

    float b_log[9];                        // logits in log2 domain
    const int wv = tid >> 6;               // wave id 0..3

    // -------- iter 0: ck == 1/16 -> PACKED allreduce of SVp, zero cvt --------
    {
        half2_t spk[8];
        #pragma unroll
        for (int j = 0; j < 8; ++j) spk[j] = allred16_pk(SVp[j]);

        float n2S = 0.0f;                  // Σ S² via dot2 on packed
        #pragma unroll
        for (int j = 0; j < 8; ++j) n2S = __builtin_amdgcn_fdot2(spk[j], spk[j], n2S, false);
        const float n2 = n2S * (1.0f / 256.0f);                      // ||S/16||^2
        const float g = n2 * __builtin_amdgcn_rcpf(1.0f + n2)
                           * __builtin_amdgcn_rsqf(n2 + CAPS_EPS);
        const float gl2 = g * (0.0625f * LOG2E);                     // log2-domain

        #pragma unroll
        for (int k = 0; k < 9; ++k) {
            float dot = 0.0f;
            #pragma unroll
            for (int j = 0; j < 8; ++j)
                dot = __builtin_amdgcn_fdot2(Vp[k][j], spk[j], dot, false);
            b_log[k] = gl2 * dot;
        }
    }

    // -------- iter 1: softmax + PACKED weighted accum + packed allreduce --------
    {
        float eb[9], ebs[9];
        #pragma unroll
        for (int k = 0; k < 9; ++k) { eb[k] = EXP2(b_log[k]); ebs[k] = eb[k]; }
        #pragma unroll
        for (int k = 0; k < 9; ++k) {
            ebs[k] += xswap16(ebs[k], lane);           // xor16 (VALU permlane)
            ebs[k] += xswap32(ebs[k], lane);           // xor32 (VALU permlane)
        }
        if (lane < 16) {
            #pragma unroll
            for (int k = 0; k < 9; ++k)
                reinterpret_cast<float*>(&sbv[0][k * 16 + c])[wv] = ebs[k];
        }
        __syncthreads();
        half2_t ckh[9];
        #pragma unroll
        for (int k = 0; k < 9; ++k) {
            const float4 t = sbv[0][k * 16 + c];
            const float tot = (t.x + t.y) + (t.z + t.w);
            const float ck = eb[k] * __builtin_amdgcn_rcpf(tot);
            ckh[k] = __builtin_amdgcn_cvt_pkrtz(ck, ck);
        }

        half2_t s_pk[8];
        #pragma unroll
        for (int j = 0; j < 8; ++j) s_pk[j] = bc_h2(0.0f);
        #pragma unroll
        for (int k = 0; k < 9; ++k) {
            #pragma unroll
            for (int j = 0; j < 8; ++j) pkfma(s_pk[j], ckh[k], Vp[k][j]);
        }
        #pragma unroll
        for (int j = 0; j < 8; ++j) s_pk[j] = allred16_pk(s_pk[j]);

        float n2S = 0.0f;
        #pragma unroll
        for (int j = 0; j < 8; ++j) n2S = __builtin_amdgcn_fdot2(s_pk[j], s_pk[j], n2S, false);
        const float g = n2S * __builtin_amdgcn_rcpf(1.0f + n2S)
                            * __builtin_amdgcn_rsqf(n2S + CAPS_EPS);
        const float gl2 = g * LOG2E;

        #pragma unroll
        for (int k = 0; k < 9; ++k) {
            float dot = 0.0f;
            #pragma unroll
            for (int j = 0; j < 8; ++j)
                dot = __builtin_amdgcn_fdot2(Vp[k][j], s_pk[j], dot, false);
            b_log[k] = fmaf(gl2, dot, b_log[k]);
        }
    }

    // -------- iter 2 (OUTPUT path, f32): reduce-scatter, no allgather --------
    {
        float eb[9], ebs[9];
        #pragma unroll
        for (int k = 0; k < 9; ++k) { eb[k] = EXP2(b_log[k]); ebs[k] = eb[k]; }
        #pragma unroll
        for (int k = 0; k < 9; ++k) {
            ebs[k] += xswap16(ebs[k], lane);
            ebs[k] += xswap32(ebs[k], lane);
        }
        if (lane < 16) {
            #pragma unroll
            for (int k = 0; k < 9; ++k)
                reinterpret_cast<float*>(&sbv[1][k * 16 + c])[wv] = ebs[k];
        }
        __syncthreads();
        float ck[9];
        #pragma unroll
        for (int k = 0; k < 9; ++k) {
            const float4 t = sbv[1][k * 16 + c];
            const float tot = (t.x + t.y) + (t.z + t.w);
            ck[k] = eb[k] * __builtin_amdgcn_rcpf(tot);
        }

        float s[16];
        #pragma unroll
        for (int d = 0; d < 16; ++d) s[d] = 0.0f;
        #pragma unroll
        for (int k = 0; k < 9; ++k) {
            const float ckk = ck[k];
            #pragma unroll
            for (int j = 0; j < 8; ++j) {
                fmamix_lo(s[2 * j],     ckk, Vp[k][j]);
                fmamix_hi(s[2 * j + 1], ckk, Vp[k][j]);
            }
        }
        // recursive-halving reduce-scatter: send the half the PARTNER keeps
        const bool k8 = (c & 8) != 0;
        float t8[8];
        #pragma unroll
        for (int j = 0; j < 8; ++j) {
            const float keep = k8 ? s[j + 8] : s[j];
            const float send = k8 ? s[j] : s[j + 8];
            t8[j] = keep + mov_dpp_f<0x128>(send);     // ror8 == xor8 within 16
        }
        const bool k4 = (c & 4) != 0;
        float t4[4];
        #pragma unroll
        for (int j = 0; j < 4; ++j) {
            const float keep = k4 ? t8[j + 4] : t8[j];
            const float send = k4 ? t8[j] : t8[j + 4];
            t4[j] = keep + mov_sw_f<0x101F>(send);     // exact xor4 (swizzle)
        }
        const bool k2 = (c & 2) != 0;
        float t2[2];
        #pragma unroll
        for (int j = 0; j < 2; ++j) {
            const float keep = k2 ? t4[j + 2] : t4[j];
            const float send = k2 ? t4[j] : t4[j + 2];
            t2[j] = keep + mov_dpp_f<0x4E>(send);
        }
        const bool k1 = (c & 1) != 0;
        const float z = (k1 ? t2[1] : t2[0]) + mov_dpp_f<0xB1>(k1 ? t2[0] : t2[1]);
        // z == fully-reduced s[c] on lane c

        const float n2 = allred16(z * z);              // ||s||^2 over the 16-group

        const float scale = n2 * __builtin_amdgcn_rcpf(1.0f + n2)
                               * __builtin_amdgcn_rsqf(n2 + CAPS_EPS);
        out[(size_t)pos * 256 + n * 16 + c] = z * scale;   // fully coalesced

        if (c == 0) {
            const float m2 = n2 * scale * scale;           // ||v||^2
            const float sc2 = m2 * __builtin_amdgcn_rcpf(1.0f + m2)
                                 * __builtin_amdgcn_rsqf(m2 + CAPS_EPS);
            out[921600 + (size_t)pos * 16 + n] = sqrtf(m2 * sc2 * sc2 + CAPS_EPS);
        }
    }
}

extern "C" void kernel_launch(void* const* d_in, const int* in_sizes, int n_in,
                              void* d_out, int out_size, void* d_ws, size_t ws_size,
                              hipStream_t stream) {
    const float* poses = (const float*)d_in[0];
    // d_in[1] = input_activations: unused by the reference computation
    const float* kern  = (const float*)d_in[2];
    float* out = (float*)d_out;
    half2_t* wpk = (half2_t*)d_ws;         // 73728 B of scratch

    pack_weights<<<dim3(144), dim3(256), 0, stream>>>(kern, wpk);
    caps_route<<<dim3(3600), dim3(256), 0, stream>>>(poses, wpk, out);
}